// Round 25
// baseline (84.500 us; speedup 1.0000x reference)
//
#include <hip/hip_runtime.h>
#include <hip/hip_bf16.h>

#define NN 8192
#define F 64
#define ALPHA 0.2f
#define L2E 1.44269504f
#define DBOUND 16.0f
#define G 16
#define COLS (NN / G)        // 512
#define NSTEPS (COLS / 32)   // 16
#define NTILE (COLS / 32)    // B-tiles per group
#define NCHUNK (NSTEPS / 8)  // 2
#define RPB 64               // rows per attn block (4 waves)

typedef __attribute__((ext_vector_type(8))) short short8;
typedef __attribute__((ext_vector_type(4))) float f32x4;
typedef __attribute__((ext_vector_type(4))) int i32x4;

__device__ __forceinline__ unsigned fb(float x) {
    return __builtin_bit_cast(unsigned, x);
}
__device__ __forceinline__ short f2bf(float x) {
    union { float f; unsigned u; } v; v.f = x;
    unsigned r = v.u + 0x7FFF + ((v.u >> 16) & 1);
    return (short)(r >> 16);
}

// Kernel A: Wh = h @ W^T (fp32); WhTt written DIRECTLY in MFMA-fragment
// order (R14-verified index algebra); src = Wh@a1; dst2 = (Wh@a2)*log2e.
__global__ __launch_bounds__(256) void k_prep(const float* __restrict__ h,
        const float* __restrict__ W, const float* __restrict__ a,
        short* __restrict__ WhTt, float* __restrict__ src, float* __restrict__ dst2) {
    __shared__ float Wl[F][F + 1];
    __shared__ short shT[F][4];
    int tid = threadIdx.x;
    for (int m = 0; m < 4; ++m) {
        int idx = m * 1024 + tid * 4;
        float4 v = *(const float4*)&W[idx];
        int row = idx >> 6, col = idx & 63;
        Wl[row][col] = v.x; Wl[row][col + 1] = v.y;
        Wl[row][col + 2] = v.z; Wl[row][col + 3] = v.w;
    }
    __syncthreads();
    int w = tid >> 6, lane = tid & 63;
    int i = blockIdx.x * 4 + w;
    const float* hrow = &h[(size_t)i * F];
    float wh = 0.f;
    #pragma unroll
    for (int k = 0; k < F; k += 4) {
        float4 hv = *(const float4*)&hrow[k];
        wh += hv.x * Wl[lane][k] + hv.y * Wl[lane][k + 1]
            + hv.z * Wl[lane][k + 2] + hv.w * Wl[lane][k + 3];
    }
    shT[lane][w] = f2bf(wh);
    float s1 = wh * a[lane];
    float s2 = wh * a[F + lane];
    #pragma unroll
    for (int off = 32; off; off >>= 1) {
        s1 += __shfl_xor(s1, off);
        s2 += __shfl_xor(s2, off);
    }
    if (lane == 0) { src[i] = s1; dst2[i] = s2 * L2E; }
    __syncthreads();
    if (tid < F) {
        int f = tid;
        int b = blockIdx.x;
        int t = b >> 3;
        int off = (b * 4) & 31;
        size_t addr = (((size_t)(t * 4 + (f >> 4)) * 64
                       + (off >> 3) * 16 + (f & 15)) << 3) + (off & 7);
        short4 v = make_short4(shT[f][0], shT[f][1], shT[f][2], shT[f][3]);
        *(short4*)&WhTt[addr] = v;
    }
}

// Kernel B: FULLY FUSED attention (R23 winner), G=16 -> 2048 blocks =
// 4 blocks/CU, 16 waves/CU: block prologues/barriers hide under co-resident
// blocks; outstanding HBM requests double. Inner loops verbatim R23.
__global__ __launch_bounds__(256, 4) void k_attn(const int* __restrict__ adj,
        const short8* __restrict__ WhTt, const float* __restrict__ src,
        const float* __restrict__ dst2,
        float* __restrict__ Opart, float* __restrict__ lpart) {
    __shared__ unsigned mbuf[2][RPB][9];  // [buf][row][8 dwords + pad]
    __shared__ float e1lds[COLS];         // exp2(dst2[j])
    __shared__ float e2lds[COLS];         // exp2(ALPHA*dst2[j])

    int rb = blockIdx.x / G;
    int g  = blockIdx.x % G;
    int jbase = g * COLS;
    int tid = threadIdx.x;
    int w = tid >> 6, lane = tid & 63;

    for (int idx = tid; idx < COLS; idx += 256) {
        float d = dst2[jbase + idx];
        e1lds[idx] = __builtin_amdgcn_exp2f(d);
        e2lds[idx] = __builtin_amdgcn_exp2f(d * ALPHA);
    }

    const int* arow0 = adj + (size_t)(rb * RPB) * NN + jbase;
    int sh8 = 4 * (lane & 7);

#define AISSUE(rr, cc, dst) \
    dst = __builtin_nontemporal_load( \
        (const i32x4*)(arow0 + (size_t)(rr) * NN + (size_t)(cc) * 256) + lane);

#define APACK(av, rr, buf) { \
    unsigned n = (av.x > 0 ? 1u : 0u) | (av.y > 0 ? 2u : 0u) \
               | (av.z > 0 ? 4u : 0u) | (av.w > 0 ? 8u : 0u); \
    unsigned v = n << sh8; \
    v |= __shfl_xor(v, 1); v |= __shfl_xor(v, 2); v |= __shfl_xor(v, 4); \
    if ((lane & 7) == 0) mbuf[buf][rr][lane >> 3] = v; }

    // prologue: stage chunk 0 (16 rows/wave, issued 4-deep)
    #pragma unroll
    for (int k0 = 0; k0 < 16; k0 += 4) {
        i32x4 a0, a1, a2, a3;
        AISSUE(w * 16 + k0,     0, a0) AISSUE(w * 16 + k0 + 1, 0, a1)
        AISSUE(w * 16 + k0 + 2, 0, a2) AISSUE(w * 16 + k0 + 3, 0, a3)
        APACK(a0, w * 16 + k0,     0) APACK(a1, w * 16 + k0 + 1, 0)
        APACK(a2, w * 16 + k0 + 2, 0) APACK(a3, w * 16 + k0 + 3, 0)
    }

    int r = lane & 15, q = lane >> 4;
    int qs = q * 8;
    int i = rb * RPB + w * 16 + r;

    float srcv = src[i];
    float sM = srcv + DBOUND;
    float Mi = fmaxf(sM, ALPHA * sM);
    float sL  = srcv * L2E;
    float MiL = Mi * L2E;
    float eC1 = __builtin_amdgcn_exp2f(sL - MiL);
    float eC2 = __builtin_amdgcn_exp2f(fmaf(sL, ALPHA, -MiL));

    f32x4 acc0{}, acc1{}, acc2{}, acc3{}, acc4{};
    short8 ones;
    #pragma unroll
    for (int k = 0; k < 8; ++k) ones[k] = (short)0x3F80;  // bf16 1.0

#define LDB(tt, B0, B1, B2, B3) { \
    const short8* bp = WhTt + (size_t)(g * NTILE + (tt)) * 256; \
    B0 = bp[lane]; B1 = bp[64 + lane]; B2 = bp[128 + lane]; B3 = bp[192 + lane]; }

#define PEL(u, v, bit, eo) { \
    float e = fmaxf(eC1 * (u), eC2 * (v)); \
    eo = (bit) ? e : 0.0f; }

    short8 cb0, cb1, cb2, cb3, nb0, nb1, nb2, nb3;
    LDB(0, cb0, cb1, cb2, cb3)
    __syncthreads();                      // chunk 0 mask ready

    i32x4 sa0, sa1;                       // staging pair in flight
    for (int c = 0; c < NCHUNK; ++c) {
        int buf = c & 1, nbuf = buf ^ 1;
        bool stg = (c < NCHUNK - 1);
        const unsigned* mrow = &mbuf[buf][w * 16 + r][0];

        #pragma unroll
        for (int ts = 0; ts < 8; ++ts) {
            int t = c * 8 + ts;
            if (stg && ts >= 1) {
                APACK(sa0, (ts - 1) * 8 + w * 2,     nbuf)
                APACK(sa1, (ts - 1) * 8 + w * 2 + 1, nbuf)
            }
            if (stg) {
                AISSUE(ts * 8 + w * 2,     c + 1, sa0)
                AISSUE(ts * 8 + w * 2 + 1, c + 1, sa1)
            }

            int tn = (t + 1 < NSTEPS) ? t + 1 : t;
            LDB(tn, nb0, nb1, nb2, nb3)           // L2 B-stream, dist-1

            unsigned m8 = (mrow[ts] >> qs) & 0xffu;
            float4 p0 = *(const float4*)&e1lds[t * 32 + qs];
            float4 p1 = *(const float4*)&e1lds[t * 32 + qs + 4];
            float4 q0 = *(const float4*)&e2lds[t * 32 + qs];
            float4 q1 = *(const float4*)&e2lds[t * 32 + qs + 4];

            float e0, e1, e2, e3, e4, e5, e6, e7;
            PEL(p0.x, q0.x, (m8 & 1u),   e0) PEL(p0.y, q0.y, (m8 & 2u),   e1)
            PEL(p0.z, q0.z, (m8 & 4u),   e2) PEL(p0.w, q0.w, (m8 & 8u),   e3)
            PEL(p1.x, q1.x, (m8 & 16u),  e4) PEL(p1.y, q1.y, (m8 & 32u),  e5)
            PEL(p1.z, q1.z, (m8 & 64u),  e6) PEL(p1.w, q1.w, (m8 & 128u), e7)

            unsigned w0 = __builtin_amdgcn_perm(fb(e1), fb(e0), 0x07060302u);
            unsigned w1 = __builtin_amdgcn_perm(fb(e3), fb(e2), 0x07060302u);
            unsigned w2 = __builtin_amdgcn_perm(fb(e5), fb(e4), 0x07060302u);
            unsigned w3 = __builtin_amdgcn_perm(fb(e7), fb(e6), 0x07060302u);
            short8 af = __builtin_bit_cast(short8, make_uint4(w0, w1, w2, w3));

            acc0 = __builtin_amdgcn_mfma_f32_16x16x32_bf16(af, cb0, acc0, 0, 0, 0);
            acc1 = __builtin_amdgcn_mfma_f32_16x16x32_bf16(af, cb1, acc1, 0, 0, 0);
            acc2 = __builtin_amdgcn_mfma_f32_16x16x32_bf16(af, cb2, acc2, 0, 0, 0);
            acc3 = __builtin_amdgcn_mfma_f32_16x16x32_bf16(af, cb3, acc3, 0, 0, 0);
            acc4 = __builtin_amdgcn_mfma_f32_16x16x32_bf16(af, ones, acc4, 0, 0, 0);

            cb0 = nb0; cb1 = nb1; cb2 = nb2; cb3 = nb3;

            if (stg && ts == 7) {
                APACK(sa0, 7 * 8 + w * 2,     nbuf)
                APACK(sa1, 7 * 8 + w * 2 + 1, nbuf)
            }
        }
        __syncthreads();                  // chunk c done; chunk c+1 mask ready
    }
#undef PEL
#undef LDB
#undef APACK
#undef AISSUE

    // acc4: every column holds the row-sum; C rows = q*4 + reg.
    int ic = rb * RPB + w * 16 + q * 4;
    if (r == 0) {
        #pragma unroll
        for (int reg = 0; reg < 4; ++reg)
            lpart[(size_t)g * NN + ic + reg] = acc4[reg];
    }

    size_t ob = (size_t)g * (size_t)(NN * F);
    #pragma unroll
    for (int reg = 0; reg < 4; ++reg) {
        size_t ro = ob + (size_t)(ic + reg) * F + r;
        Opart[ro]      = acc0[reg];
        Opart[ro + 16] = acc1[reg];
        Opart[ro + 32] = acc2[reg];
        Opart[ro + 48] = acc3[reg];
    }
}

// Kernel D: out = elu( (sum_g Opart) / (sum_g lpart) )
__global__ __launch_bounds__(256) void k_reduce(const float* __restrict__ Opart,
        const float* __restrict__ lpart, float* __restrict__ out) {
    int idx = blockIdx.x * 256 + threadIdx.x;
    int i = idx >> 6;
    float o = 0.f, l = 0.f;
    #pragma unroll
    for (int g = 0; g < G; ++g) {
        o += Opart[(size_t)g * (NN * F) + idx];
        l += lpart[(size_t)g * NN + i];
    }
    float hp = o / l;
    out[idx] = hp > 0.f ? hp : __expf(hp) - 1.f;
}

extern "C" void kernel_launch(void* const* d_in, const int* in_sizes, int n_in,
                              void* d_out, int out_size, void* d_ws, size_t ws_size,
                              hipStream_t stream) {
    const float* h  = (const float*)d_in[0];
    const int* adj  = (const int*)d_in[1];
    const float* W  = (const float*)d_in[2];
    const float* a  = (const float*)d_in[3];
    float* out = (float*)d_out;

    char* ws = (char*)d_ws;
    const size_t OFF_WHTT = 0;                       // 1 MB fragment-order WhTt
    const size_t OFF_SRC  = (1u << 20);              // 32 KB
    const size_t OFF_DST  = OFF_SRC + (32u << 10);   // 32 KB
    const size_t OFF_LP   = OFF_DST + (32u << 10);   // 512 KB (G*NN*4)
    const size_t OFF_OP   = OFF_LP + (size_t)G * NN * 4;      // 32 MB Opart

    short* WhTt  = (short*)(ws + OFF_WHTT);
    float* src   = (float*)(ws + OFF_SRC);
    float* dst2  = (float*)(ws + OFF_DST);
    float* lpart = (float*)(ws + OFF_LP);
    float* Opart = (float*)(ws + OFF_OP);

    k_prep<<<NN / 4, 256, 0, stream>>>(h, W, a, WhTt, src, dst2);
    k_attn<<<(NN / RPB) * G, 256, 0, stream>>>(adj, (const short8*)WhTt, src, dst2,
                                               Opart, lpart);
    k_reduce<<<(NN * F) / 256, 256, 0, stream>>>(Opart, lpart, out);
}

// Round 26
// 82.997 us; speedup vs baseline: 1.0181x; 1.0181x over previous
//
#include <hip/hip_runtime.h>
#include <hip/hip_bf16.h>

#define NN 8192
#define F 64
#define ALPHA 0.2f
#define L2E 1.44269504f
#define DBOUND 16.0f
#define G 8
#define COLS (NN / G)        // 1024
#define NSTEPS (COLS / 32)   // 32
#define RPB 32               // rows per attn block (2 waves, 128 threads)

typedef __attribute__((ext_vector_type(8))) short short8;
typedef __attribute__((ext_vector_type(4))) float f32x4;
typedef __attribute__((ext_vector_type(4))) int i32x4;

__device__ __forceinline__ unsigned fb(float x) {
    return __builtin_bit_cast(unsigned, x);
}
__device__ __forceinline__ short f2bf(float x) {
    union { float f; unsigned u; } v; v.f = x;
    unsigned r = v.u + 0x7FFF + ((v.u >> 16) & 1);
    return (short)(r >> 16);
}

// Kernel A: Wh = h @ W^T (fp32); WhTt written DIRECTLY in MFMA-fragment
// order (R14-verified index algebra); src = Wh@a1; dst2 = (Wh@a2)*log2e.
__global__ __launch_bounds__(256) void k_prep(const float* __restrict__ h,
        const float* __restrict__ W, const float* __restrict__ a,
        short* __restrict__ WhTt, float* __restrict__ src, float* __restrict__ dst2) {
    __shared__ float Wl[F][F + 1];
    __shared__ short shT[F][4];
    int tid = threadIdx.x;
    for (int m = 0; m < 4; ++m) {
        int idx = m * 1024 + tid * 4;
        float4 v = *(const float4*)&W[idx];
        int row = idx >> 6, col = idx & 63;
        Wl[row][col] = v.x; Wl[row][col + 1] = v.y;
        Wl[row][col + 2] = v.z; Wl[row][col + 3] = v.w;
    }
    __syncthreads();
    int w = tid >> 6, lane = tid & 63;
    int i = blockIdx.x * 4 + w;
    const float* hrow = &h[(size_t)i * F];
    float wh = 0.f;
    #pragma unroll
    for (int k = 0; k < F; k += 4) {
        float4 hv = *(const float4*)&hrow[k];
        wh += hv.x * Wl[lane][k] + hv.y * Wl[lane][k + 1]
            + hv.z * Wl[lane][k + 2] + hv.w * Wl[lane][k + 3];
    }
    shT[lane][w] = f2bf(wh);
    float s1 = wh * a[lane];
    float s2 = wh * a[F + lane];
    #pragma unroll
    for (int off = 32; off; off >>= 1) {
        s1 += __shfl_xor(s1, off);
        s2 += __shfl_xor(s2, off);
    }
    if (lane == 0) { src[i] = s1; dst2[i] = s2 * L2E; }
    __syncthreads();
    if (tid < F) {
        int f = tid;
        int b = blockIdx.x;
        int t = b >> 3;
        int off = (b * 4) & 31;
        size_t addr = (((size_t)(t * 4 + (f >> 4)) * 64
                       + (off >> 3) * 16 + (f & 15)) << 3) + (off & 7);
        short4 v = make_short4(shT[f][0], shT[f][1], shT[f][2], shT[f][3]);
        *(short4*)&WhTt[addr] = v;
    }
}

// Kernel B: FULLY FUSED attention (R23 structure), RPB=32 / 2-wave blocks:
// grid 2048 -> 8 blocks/CU (16 waves/CU). Block-edge stalls (prologue,
// last-chunk tail, barriers) hide under 7 co-resident neighbor blocks.
// Chip-wide adj/B/Opart traffic identical to R23.
__global__ __launch_bounds__(128, 4) void k_attn(const int* __restrict__ adj,
        const short8* __restrict__ WhTt, const float* __restrict__ src,
        const float* __restrict__ dst2,
        float* __restrict__ Opart, float* __restrict__ lpart) {
    __shared__ unsigned mbuf[2][RPB][9];  // [buf][row][8 dwords + pad]
    __shared__ float e1lds[COLS];         // exp2(dst2[j])
    __shared__ float e2lds[COLS];         // exp2(ALPHA*dst2[j])

    int rb = blockIdx.x / G;
    int g  = blockIdx.x % G;
    int jbase = g * COLS;
    int tid = threadIdx.x;
    int w = tid >> 6, lane = tid & 63;    // w in [0,2)

    for (int idx = tid; idx < COLS; idx += 128) {
        float d = dst2[jbase + idx];
        e1lds[idx] = __builtin_amdgcn_exp2f(d);
        e2lds[idx] = __builtin_amdgcn_exp2f(d * ALPHA);
    }

    const int* arow0 = adj + (size_t)(rb * RPB) * NN + jbase;
    int sh8 = 4 * (lane & 7);

#define AISSUE(rr, cc, dst) \
    dst = __builtin_nontemporal_load( \
        (const i32x4*)(arow0 + (size_t)(rr) * NN + (size_t)(cc) * 256) + lane);

#define APACK(av, rr, buf) { \
    unsigned n = (av.x > 0 ? 1u : 0u) | (av.y > 0 ? 2u : 0u) \
               | (av.z > 0 ? 4u : 0u) | (av.w > 0 ? 8u : 0u); \
    unsigned v = n << sh8; \
    v |= __shfl_xor(v, 1); v |= __shfl_xor(v, 2); v |= __shfl_xor(v, 4); \
    if ((lane & 7) == 0) mbuf[buf][rr][lane >> 3] = v; }

    // prologue: stage chunk 0 (16 rows/wave, issued 4-deep; 2 waves = 32 rows)
    #pragma unroll
    for (int k0 = 0; k0 < 16; k0 += 4) {
        i32x4 a0, a1, a2, a3;
        AISSUE(w * 16 + k0,     0, a0) AISSUE(w * 16 + k0 + 1, 0, a1)
        AISSUE(w * 16 + k0 + 2, 0, a2) AISSUE(w * 16 + k0 + 3, 0, a3)
        APACK(a0, w * 16 + k0,     0) APACK(a1, w * 16 + k0 + 1, 0)
        APACK(a2, w * 16 + k0 + 2, 0) APACK(a3, w * 16 + k0 + 3, 0)
    }

    int r = lane & 15, q = lane >> 4;
    int qs = q * 8;
    int i = rb * RPB + w * 16 + r;

    float srcv = src[i];
    float sM = srcv + DBOUND;
    float Mi = fmaxf(sM, ALPHA * sM);
    float sL  = srcv * L2E;
    float MiL = Mi * L2E;
    float eC1 = __builtin_amdgcn_exp2f(sL - MiL);
    float eC2 = __builtin_amdgcn_exp2f(fmaf(sL, ALPHA, -MiL));

    f32x4 acc0{}, acc1{}, acc2{}, acc3{}, acc4{};
    short8 ones;
    #pragma unroll
    for (int k = 0; k < 8; ++k) ones[k] = (short)0x3F80;  // bf16 1.0

#define LDB(tt, B0, B1, B2, B3) { \
    const short8* bp = WhTt + (size_t)(g * 32 + (tt)) * 256; \
    B0 = bp[lane]; B1 = bp[64 + lane]; B2 = bp[128 + lane]; B3 = bp[192 + lane]; }

#define PEL(u, v, bit, eo) { \
    float e = fmaxf(eC1 * (u), eC2 * (v)); \
    eo = (bit) ? e : 0.0f; }

    short8 cb0, cb1, cb2, cb3, nb0, nb1, nb2, nb3;
    LDB(0, cb0, cb1, cb2, cb3)
    __syncthreads();                      // chunk 0 mask ready

    i32x4 sa0, sa1;                       // staging pair in flight
    for (int c = 0; c < 4; ++c) {
        int buf = c & 1, nbuf = buf ^ 1;
        bool stg = (c < 3);
        const unsigned* mrow = &mbuf[buf][w * 16 + r][0];

        #pragma unroll
        for (int ts = 0; ts < 8; ++ts) {
            int t = c * 8 + ts;
            // pack pair issued last step (rows (ts-1)*4 + w*2, +1)
            if (stg && ts >= 1) {
                APACK(sa0, (ts - 1) * 4 + w * 2,     nbuf)
                APACK(sa1, (ts - 1) * 4 + w * 2 + 1, nbuf)
            }
            // issue this step's pair for chunk c+1 (rows ts*4 + w*2, +1)
            if (stg) {
                AISSUE(ts * 4 + w * 2,     c + 1, sa0)
                AISSUE(ts * 4 + w * 2 + 1, c + 1, sa1)
            }

            int tn = (t + 1 < NSTEPS) ? t + 1 : t;
            LDB(tn, nb0, nb1, nb2, nb3)           // L2 B-stream, dist-1

            unsigned m8 = (mrow[ts] >> qs) & 0xffu;
            float4 p0 = *(const float4*)&e1lds[t * 32 + qs];
            float4 p1 = *(const float4*)&e1lds[t * 32 + qs + 4];
            float4 q0 = *(const float4*)&e2lds[t * 32 + qs];
            float4 q1 = *(const float4*)&e2lds[t * 32 + qs + 4];

            float e0, e1, e2, e3, e4, e5, e6, e7;
            PEL(p0.x, q0.x, (m8 & 1u),   e0) PEL(p0.y, q0.y, (m8 & 2u),   e1)
            PEL(p0.z, q0.z, (m8 & 4u),   e2) PEL(p0.w, q0.w, (m8 & 8u),   e3)
            PEL(p1.x, q1.x, (m8 & 16u),  e4) PEL(p1.y, q1.y, (m8 & 32u),  e5)
            PEL(p1.z, q1.z, (m8 & 64u),  e6) PEL(p1.w, q1.w, (m8 & 128u), e7)

            unsigned w0 = __builtin_amdgcn_perm(fb(e1), fb(e0), 0x07060302u);
            unsigned w1 = __builtin_amdgcn_perm(fb(e3), fb(e2), 0x07060302u);
            unsigned w2 = __builtin_amdgcn_perm(fb(e5), fb(e4), 0x07060302u);
            unsigned w3 = __builtin_amdgcn_perm(fb(e7), fb(e6), 0x07060302u);
            short8 af = __builtin_bit_cast(short8, make_uint4(w0, w1, w2, w3));

            acc0 = __builtin_amdgcn_mfma_f32_16x16x32_bf16(af, cb0, acc0, 0, 0, 0);
            acc1 = __builtin_amdgcn_mfma_f32_16x16x32_bf16(af, cb1, acc1, 0, 0, 0);
            acc2 = __builtin_amdgcn_mfma_f32_16x16x32_bf16(af, cb2, acc2, 0, 0, 0);
            acc3 = __builtin_amdgcn_mfma_f32_16x16x32_bf16(af, cb3, acc3, 0, 0, 0);
            acc4 = __builtin_amdgcn_mfma_f32_16x16x32_bf16(af, ones, acc4, 0, 0, 0);

            cb0 = nb0; cb1 = nb1; cb2 = nb2; cb3 = nb3;

            if (stg && ts == 7) {
                APACK(sa0, 7 * 4 + w * 2,     nbuf)
                APACK(sa1, 7 * 4 + w * 2 + 1, nbuf)
            }
        }
        __syncthreads();                  // chunk c done; chunk c+1 mask ready
    }
#undef PEL
#undef LDB
#undef APACK
#undef AISSUE

    // acc4: every column holds the row-sum; C rows = q*4 + reg.
    int ic = rb * RPB + w * 16 + q * 4;
    if (r == 0) {
        #pragma unroll
        for (int reg = 0; reg < 4; ++reg)
            lpart[(size_t)g * NN + ic + reg] = acc4[reg];
    }

    size_t ob = (size_t)g * (size_t)(NN * F);
    #pragma unroll
    for (int reg = 0; reg < 4; ++reg) {
        size_t ro = ob + (size_t)(ic + reg) * F + r;
        Opart[ro]      = acc0[reg];
        Opart[ro + 16] = acc1[reg];
        Opart[ro + 32] = acc2[reg];
        Opart[ro + 48] = acc3[reg];
    }
}

// Kernel D: out = elu( (sum_g Opart) / (sum_g lpart) )
__global__ __launch_bounds__(256) void k_reduce(const float* __restrict__ Opart,
        const float* __restrict__ lpart, float* __restrict__ out) {
    int idx = blockIdx.x * 256 + threadIdx.x;
    int i = idx >> 6;
    float o = 0.f, l = 0.f;
    #pragma unroll
    for (int g = 0; g < G; ++g) {
        o += Opart[(size_t)g * (NN * F) + idx];
        l += lpart[(size_t)g * NN + i];
    }
    float hp = o / l;
    out[idx] = hp > 0.f ? hp : __expf(hp) - 1.f;
}

extern "C" void kernel_launch(void* const* d_in, const int* in_sizes, int n_in,
                              void* d_out, int out_size, void* d_ws, size_t ws_size,
                              hipStream_t stream) {
    const float* h  = (const float*)d_in[0];
    const int* adj  = (const int*)d_in[1];
    const float* W  = (const float*)d_in[2];
    const float* a  = (const float*)d_in[3];
    float* out = (float*)d_out;

    char* ws = (char*)d_ws;
    const size_t OFF_WHTT = 0;                       // 1 MB fragment-order WhTt
    const size_t OFF_SRC  = (1u << 20);              // 32 KB
    const size_t OFF_DST  = OFF_SRC + (32u << 10);   // 32 KB
    const size_t OFF_LP   = OFF_DST + (32u << 10);   // 256 KB (G*NN*4)
    const size_t OFF_OP   = OFF_LP + (size_t)G * NN * 4;      // 16 MB Opart

    short* WhTt  = (short*)(ws + OFF_WHTT);
    float* src   = (float*)(ws + OFF_SRC);
    float* dst2  = (float*)(ws + OFF_DST);
    float* lpart = (float*)(ws + OFF_LP);
    float* Opart = (float*)(ws + OFF_OP);

    k_prep<<<NN / 4, 256, 0, stream>>>(h, W, a, WhTt, src, dst2);
    k_attn<<<(NN / RPB) * G, 128, 0, stream>>>(adj, (const short8*)WhTt, src, dst2,
                                               Opart, lpart);
    k_reduce<<<(NN * F) / 256, 256, 0, stream>>>(Opart, lpart, out);
}

// Round 27
// 78.307 us; speedup vs baseline: 1.0791x; 1.0599x over previous
//
#include <hip/hip_runtime.h>
#include <hip/hip_bf16.h>

#define NN 8192
#define F 64
#define ALPHA 0.2f
#define L2E 1.44269504f
#define DBOUND 16.0f
#define G 8
#define COLS (NN / G)        // 1024
#define NSTEPS (COLS / 32)   // 32
#define RPB 64               // rows per attn block (4 waves)

typedef __attribute__((ext_vector_type(8))) short short8;
typedef __attribute__((ext_vector_type(4))) float f32x4;
typedef __attribute__((ext_vector_type(4))) int i32x4;

__device__ __forceinline__ unsigned fb(float x) {
    return __builtin_bit_cast(unsigned, x);
}
__device__ __forceinline__ short f2bf(float x) {
    union { float f; unsigned u; } v; v.f = x;
    unsigned r = v.u + 0x7FFF + ((v.u >> 16) & 1);
    return (short)(r >> 16);
}

// Kernel A: Wh = h @ W^T (fp32); WhTt written DIRECTLY in MFMA-fragment
// order (R14-verified index algebra); src = Wh@a1; dst2 = (Wh@a2)*log2e.
__global__ __launch_bounds__(256) void k_prep(const float* __restrict__ h,
        const float* __restrict__ W, const float* __restrict__ a,
        short* __restrict__ WhTt, float* __restrict__ src, float* __restrict__ dst2) {
    __shared__ float Wl[F][F + 1];
    __shared__ short shT[F][4];
    int tid = threadIdx.x;
    for (int m = 0; m < 4; ++m) {
        int idx = m * 1024 + tid * 4;
        float4 v = *(const float4*)&W[idx];
        int row = idx >> 6, col = idx & 63;
        Wl[row][col] = v.x; Wl[row][col + 1] = v.y;
        Wl[row][col + 2] = v.z; Wl[row][col + 3] = v.w;
    }
    __syncthreads();
    int w = tid >> 6, lane = tid & 63;
    int i = blockIdx.x * 4 + w;
    const float* hrow = &h[(size_t)i * F];
    float wh = 0.f;
    #pragma unroll
    for (int k = 0; k < F; k += 4) {
        float4 hv = *(const float4*)&hrow[k];
        wh += hv.x * Wl[lane][k] + hv.y * Wl[lane][k + 1]
            + hv.z * Wl[lane][k + 2] + hv.w * Wl[lane][k + 3];
    }
    shT[lane][w] = f2bf(wh);
    float s1 = wh * a[lane];
    float s2 = wh * a[F + lane];
    #pragma unroll
    for (int off = 32; off; off >>= 1) {
        s1 += __shfl_xor(s1, off);
        s2 += __shfl_xor(s2, off);
    }
    if (lane == 0) { src[i] = s1; dst2[i] = s2 * L2E; }
    __syncthreads();
    if (tid < F) {
        int f = tid;
        int b = blockIdx.x;
        int t = b >> 3;
        int off = (b * 4) & 31;
        size_t addr = (((size_t)(t * 4 + (f >> 4)) * 64
                       + (off >> 3) * 16 + (f & 15)) << 3) + (off & 7);
        short4 v = make_short4(shT[f][0], shT[f][1], shT[f][2], shT[f][3]);
        *(short4*)&WhTt[addr] = v;
    }
}

// Kernel B: FULLY FUSED attention (R23 winner, restored verbatim). adj is
// read DIRECTLY in the 1KB wave-linear NT pattern and packed to bits in a
// double-buffered LDS mask, staged STAGGERED: every wave stages 2 rows per
// compute step (pair packed one step after issue). One barrier per 8-step
// chunk. Consume loop: exp-free tables, dist-1 L2 B-stream.
__global__ __launch_bounds__(256, 4) void k_attn(const int* __restrict__ adj,
        const short8* __restrict__ WhTt, const float* __restrict__ src,
        const float* __restrict__ dst2,
        float* __restrict__ Opart, float* __restrict__ lpart) {
    __shared__ unsigned mbuf[2][RPB][9];  // [buf][row][8 dwords + pad]
    __shared__ float e1lds[COLS];         // exp2(dst2[j])
    __shared__ float e2lds[COLS];         // exp2(ALPHA*dst2[j])

    int rb = blockIdx.x / G;
    int g  = blockIdx.x % G;
    int jbase = g * COLS;
    int tid = threadIdx.x;
    int w = tid >> 6, lane = tid & 63;

    for (int idx = tid; idx < COLS; idx += 256) {
        float d = dst2[jbase + idx];
        e1lds[idx] = __builtin_amdgcn_exp2f(d);
        e2lds[idx] = __builtin_amdgcn_exp2f(d * ALPHA);
    }

    const int* arow0 = adj + (size_t)(rb * RPB) * NN + jbase;
    int sh8 = 4 * (lane & 7);

#define AISSUE(rr, cc, dst) \
    dst = __builtin_nontemporal_load( \
        (const i32x4*)(arow0 + (size_t)(rr) * NN + (size_t)(cc) * 256) + lane);

#define APACK(av, rr, buf) { \
    unsigned n = (av.x > 0 ? 1u : 0u) | (av.y > 0 ? 2u : 0u) \
               | (av.z > 0 ? 4u : 0u) | (av.w > 0 ? 8u : 0u); \
    unsigned v = n << sh8; \
    v |= __shfl_xor(v, 1); v |= __shfl_xor(v, 2); v |= __shfl_xor(v, 4); \
    if ((lane & 7) == 0) mbuf[buf][rr][lane >> 3] = v; }

    // prologue: stage chunk 0 (16 rows/wave, issued 4-deep)
    #pragma unroll
    for (int k0 = 0; k0 < 16; k0 += 4) {
        i32x4 a0, a1, a2, a3;
        AISSUE(w * 16 + k0,     0, a0) AISSUE(w * 16 + k0 + 1, 0, a1)
        AISSUE(w * 16 + k0 + 2, 0, a2) AISSUE(w * 16 + k0 + 3, 0, a3)
        APACK(a0, w * 16 + k0,     0) APACK(a1, w * 16 + k0 + 1, 0)
        APACK(a2, w * 16 + k0 + 2, 0) APACK(a3, w * 16 + k0 + 3, 0)
    }

    int r = lane & 15, q = lane >> 4;
    int qs = q * 8;
    int i = rb * RPB + w * 16 + r;

    float srcv = src[i];
    float sM = srcv + DBOUND;
    float Mi = fmaxf(sM, ALPHA * sM);
    float sL  = srcv * L2E;
    float MiL = Mi * L2E;
    float eC1 = __builtin_amdgcn_exp2f(sL - MiL);
    float eC2 = __builtin_amdgcn_exp2f(fmaf(sL, ALPHA, -MiL));

    f32x4 acc0{}, acc1{}, acc2{}, acc3{}, acc4{};
    short8 ones;
    #pragma unroll
    for (int k = 0; k < 8; ++k) ones[k] = (short)0x3F80;  // bf16 1.0

#define LDB(tt, B0, B1, B2, B3) { \
    const short8* bp = WhTt + (size_t)(g * 32 + (tt)) * 256; \
    B0 = bp[lane]; B1 = bp[64 + lane]; B2 = bp[128 + lane]; B3 = bp[192 + lane]; }

#define PEL(u, v, bit, eo) { \
    float e = fmaxf(eC1 * (u), eC2 * (v)); \
    eo = (bit) ? e : 0.0f; }

    short8 cb0, cb1, cb2, cb3, nb0, nb1, nb2, nb3;
    LDB(0, cb0, cb1, cb2, cb3)
    __syncthreads();                      // chunk 0 mask ready

    i32x4 sa0, sa1;                       // staging pair in flight
    for (int c = 0; c < 4; ++c) {
        int buf = c & 1, nbuf = buf ^ 1;
        bool stg = (c < 3);
        const unsigned* mrow = &mbuf[buf][w * 16 + r][0];

        #pragma unroll
        for (int ts = 0; ts < 8; ++ts) {
            int t = c * 8 + ts;
            // pack pair issued last step (rows (ts-1)*8 + w*2, +1)
            if (stg && ts >= 1) {
                APACK(sa0, (ts - 1) * 8 + w * 2,     nbuf)
                APACK(sa1, (ts - 1) * 8 + w * 2 + 1, nbuf)
            }
            // issue this step's pair for chunk c+1 (rows ts*8 + w*2, +1)
            if (stg) {
                AISSUE(ts * 8 + w * 2,     c + 1, sa0)
                AISSUE(ts * 8 + w * 2 + 1, c + 1, sa1)
            }

            int tn = (t + 1 < NSTEPS) ? t + 1 : t;
            LDB(tn, nb0, nb1, nb2, nb3)           // L2 B-stream, dist-1

            unsigned m8 = (mrow[ts] >> qs) & 0xffu;
            float4 p0 = *(const float4*)&e1lds[t * 32 + qs];
            float4 p1 = *(const float4*)&e1lds[t * 32 + qs + 4];
            float4 q0 = *(const float4*)&e2lds[t * 32 + qs];
            float4 q1 = *(const float4*)&e2lds[t * 32 + qs + 4];

            float e0, e1, e2, e3, e4, e5, e6, e7;
            PEL(p0.x, q0.x, (m8 & 1u),   e0) PEL(p0.y, q0.y, (m8 & 2u),   e1)
            PEL(p0.z, q0.z, (m8 & 4u),   e2) PEL(p0.w, q0.w, (m8 & 8u),   e3)
            PEL(p1.x, q1.x, (m8 & 16u),  e4) PEL(p1.y, q1.y, (m8 & 32u),  e5)
            PEL(p1.z, q1.z, (m8 & 64u),  e6) PEL(p1.w, q1.w, (m8 & 128u), e7)

            unsigned w0 = __builtin_amdgcn_perm(fb(e1), fb(e0), 0x07060302u);
            unsigned w1 = __builtin_amdgcn_perm(fb(e3), fb(e2), 0x07060302u);
            unsigned w2 = __builtin_amdgcn_perm(fb(e5), fb(e4), 0x07060302u);
            unsigned w3 = __builtin_amdgcn_perm(fb(e7), fb(e6), 0x07060302u);
            short8 af = __builtin_bit_cast(short8, make_uint4(w0, w1, w2, w3));

            acc0 = __builtin_amdgcn_mfma_f32_16x16x32_bf16(af, cb0, acc0, 0, 0, 0);
            acc1 = __builtin_amdgcn_mfma_f32_16x16x32_bf16(af, cb1, acc1, 0, 0, 0);
            acc2 = __builtin_amdgcn_mfma_f32_16x16x32_bf16(af, cb2, acc2, 0, 0, 0);
            acc3 = __builtin_amdgcn_mfma_f32_16x16x32_bf16(af, cb3, acc3, 0, 0, 0);
            acc4 = __builtin_amdgcn_mfma_f32_16x16x32_bf16(af, ones, acc4, 0, 0, 0);

            cb0 = nb0; cb1 = nb1; cb2 = nb2; cb3 = nb3;

            // last pair of the chunk: pack at end of step (issued above)
            if (stg && ts == 7) {
                APACK(sa0, 7 * 8 + w * 2,     nbuf)
                APACK(sa1, 7 * 8 + w * 2 + 1, nbuf)
            }
        }
        __syncthreads();                  // chunk c done; chunk c+1 mask ready
    }
#undef PEL
#undef LDB
#undef APACK
#undef AISSUE

    // acc4: every column holds the row-sum; C rows = q*4 + reg.
    int ic = rb * RPB + w * 16 + q * 4;
    if (r == 0) {
        #pragma unroll
        for (int reg = 0; reg < 4; ++reg)
            lpart[(size_t)g * NN + ic + reg] = acc4[reg];
    }

    size_t ob = (size_t)g * (size_t)(NN * F);
    #pragma unroll
    for (int reg = 0; reg < 4; ++reg) {
        size_t ro = ob + (size_t)(ic + reg) * F + r;
        Opart[ro]      = acc0[reg];
        Opart[ro + 16] = acc1[reg];
        Opart[ro + 32] = acc2[reg];
        Opart[ro + 48] = acc3[reg];
    }
}

// Kernel D: out = elu( (sum_g Opart) / (sum_g lpart) )
__global__ __launch_bounds__(256) void k_reduce(const float* __restrict__ Opart,
        const float* __restrict__ lpart, float* __restrict__ out) {
    int idx = blockIdx.x * 256 + threadIdx.x;
    int i = idx >> 6;
    float o = 0.f, l = 0.f;
    #pragma unroll
    for (int g = 0; g < G; ++g) {
        o += Opart[(size_t)g * (NN * F) + idx];
        l += lpart[(size_t)g * NN + i];
    }
    float hp = o / l;
    out[idx] = hp > 0.f ? hp : __expf(hp) - 1.f;
}

extern "C" void kernel_launch(void* const* d_in, const int* in_sizes, int n_in,
                              void* d_out, int out_size, void* d_ws, size_t ws_size,
                              hipStream_t stream) {
    const float* h  = (const float*)d_in[0];
    const int* adj  = (const int*)d_in[1];
    const float* W  = (const float*)d_in[2];
    const float* a  = (const float*)d_in[3];
    float* out = (float*)d_out;

    char* ws = (char*)d_ws;
    const size_t OFF_WHTT = 0;                       // 1 MB fragment-order WhTt
    const size_t OFF_SRC  = (1u << 20);              // 32 KB
    const size_t OFF_DST  = OFF_SRC + (32u << 10);   // 32 KB
    const size_t OFF_LP   = OFF_DST + (32u << 10);   // 256 KB (G*NN*4)
    const size_t OFF_OP   = OFF_LP + (size_t)G * NN * 4;      // 16 MB Opart

    short* WhTt  = (short*)(ws + OFF_WHTT);
    float* src   = (float*)(ws + OFF_SRC);
    float* dst2  = (float*)(ws + OFF_DST);
    float* lpart = (float*)(ws + OFF_LP);
    float* Opart = (float*)(ws + OFF_OP);

    k_prep<<<NN / 4, 256, 0, stream>>>(h, W, a, WhTt, src, dst2);
    k_attn<<<(NN / RPB) * G, 256, 0, stream>>>(adj, (const short8*)WhTt, src, dst2,
                                               Opart, lpart);
    k_reduce<<<(NN * F) / 256, 256, 0, stream>>>(Opart, lpart, out);
}